// Round 3
// baseline (204.557 us; speedup 1.0000x reference)
//
#include <hip/hip_runtime.h>
#include <hip/hip_bf16.h>
#include <stdint.h>

// Problem constants (B=4, L=4096, D=1024, K=3)
#define B_SZ   4
#define L_SEQ  4096
#define D_DIM  1024
#define M_TOT  (B_SZ * L_SEQ)   // 16384

typedef __bf16 bf16;
typedef __attribute__((ext_vector_type(8))) __bf16 bf16x8;
typedef __attribute__((ext_vector_type(4))) float   f32x4;

#define GLOAD_LDS16(g, l)                                                     \
  __builtin_amdgcn_global_load_lds(                                           \
      (const __attribute__((address_space(1))) void*)(g),                     \
      (__attribute__((address_space(3))) void*)(l), 16, 0, 0)

// ---------------------------------------------------------------------------
// Kernel 1: causal depthwise conv (K=3) + bf16 cast, fully parallel:
// one block per output row m (16384 blocks), each thread 4 channels with
// 3 independent float4 loads (rows m-2, m-1, m). No serial window -> latency
// hidden by massive TLP. Re-reads served by L2/LLC.
// Blocks [M_TOT, M_TOT+512) instead convert w_pw fp32->bf16 (merged launch).
// ---------------------------------------------------------------------------
__global__ __launch_bounds__(256) void dw_bf16_kernel(
    const float* __restrict__ x, const float* __restrict__ w_dw,
    const float* __restrict__ b_dw, bf16* __restrict__ y,
    const float* __restrict__ w_pw, bf16* __restrict__ wpwb) {
  const int t = threadIdx.x;
  if (blockIdx.x >= M_TOT) {
    // --- w_pw fp32 -> bf16 (512 blocks x 256 thr x 8 elems = 1M) ---
    int i = ((blockIdx.x - M_TOT) * 256 + t) * 8;
    float4 a = *(const float4*)(w_pw + i);
    float4 b = *(const float4*)(w_pw + i + 4);
    union { bf16 h[8]; int4 v; } r;
    r.h[0] = (bf16)a.x; r.h[1] = (bf16)a.y; r.h[2] = (bf16)a.z; r.h[3] = (bf16)a.w;
    r.h[4] = (bf16)b.x; r.h[5] = (bf16)b.y; r.h[6] = (bf16)b.z; r.h[7] = (bf16)b.w;
    *(int4*)(wpwb + i) = r.v;
    return;
  }
  const int m  = blockIdx.x;
  const int l  = m & (L_SEQ - 1);
  const int d0 = t * 4;
  const float* xr = x + (size_t)m * D_DIM + d0;

  const float4 zero = make_float4(0.f, 0.f, 0.f, 0.f);
  float4 x2 = (l >= 2) ? *(const float4*)(xr - 2 * D_DIM) : zero;
  float4 x1 = (l >= 1) ? *(const float4*)(xr - D_DIM) : zero;
  float4 x0 = *(const float4*)(xr);

  // w_dw rows d0..d0+3 are 12 contiguous floats at w_dw + d0*3 (48B aligned)
  const float* wp = w_dw + d0 * 3;
  float4 wa = *(const float4*)(wp);      // d0:k0,k1,k2  d1:k0
  float4 wb = *(const float4*)(wp + 4);  // d1:k1,k2     d2:k0,k1
  float4 wc = *(const float4*)(wp + 8);  // d2:k2        d3:k0,k1,k2
  float4 bv = *(const float4*)(b_dw + d0);

  float a0 = fmaf(x2.x, wa.x, fmaf(x1.x, wa.y, fmaf(x0.x, wa.z, bv.x)));
  float a1 = fmaf(x2.y, wa.w, fmaf(x1.y, wb.x, fmaf(x0.y, wb.y, bv.y)));
  float a2 = fmaf(x2.z, wb.z, fmaf(x1.z, wb.w, fmaf(x0.z, wc.x, bv.z)));
  float a3 = fmaf(x2.w, wc.y, fmaf(x1.w, wc.z, fmaf(x0.w, wc.w, bv.w)));

  union { bf16 h[4]; int2 v; } o;
  o.h[0] = (bf16)a0; o.h[1] = (bf16)a1; o.h[2] = (bf16)a2; o.h[3] = (bf16)a3;
  *(int2*)(y + (size_t)m * D_DIM + d0) = o.v;
}

// ---------------------------------------------------------------------------
// Kernel 2: GEMM  out[m][n] = sum_k y[m][k] * w_pw[n][k] + b_pw[n]
// M=16384, N=1024, K=1024. BM=BN=128, BK=32, single-barrier double-buffer:
//   stage(0); for it: { barrier; stage(it+1 -> other buf); compute(it); }
// The compiler's vmcnt(0)-before-barrier now drains DMAs issued one full
// compute phase earlier (overlapped) instead of immediately (exposed).
// LDS: 2 x (A 8KB + B 8KB) = 32KB (same occupancy as round 2).
// Swizzle for 64B rows: slot s -> row=s>>2, global chunk gc=(s&3)^((row>>1)&3)
//   => frag ds_read_b128 max 2-way on banks (free, m136).
// Grid (8,128): blockId%8 = n-block => each XCD owns one n-column; its 256KB
//   B-slice stays L2-resident; A streams via LLC.
// Epilogue: per-wave LDS transpose -> float4 stores (64MB exact, round 2).
// ---------------------------------------------------------------------------
#define BM 128
#define BN 128
#define BK 32
#define EP_ROWP 68   // fp32 per padded epilogue row

__global__ __launch_bounds__(256) void gemm_bt_kernel(
    const bf16* __restrict__ A,   // M x K row-major (y, bf16)
    const bf16* __restrict__ Bm,  // N x K row-major (w_pw, bf16)
    const float* __restrict__ bias, float* __restrict__ C) {
  __shared__ __align__(16) char smem[32768];
  // buf p: A at p*16384, B at p*16384 + 8192

  const int t    = threadIdx.x;
  const int n0   = blockIdx.x * BN;   // grid.x = 8  (n)
  const int m0   = blockIdx.y * BM;   // grid.y = 128 (m)
  const int lane = t & 63;
  const int wv   = t >> 6;
  const int wm   = (wv >> 1) * 64;
  const int wn   = (wv & 1) * 64;
  const int lrow = lane & 15;
  const int q    = lane >> 4;

  f32x4 acc[4][4] = {};

  // staging slot geometry: s = i*256 + t, i<2; 512 slots x 16B = 8KB tile
  int srow[2], sgc[2];
#pragma unroll
  for (int i = 0; i < 2; ++i) {
    int s   = i * 256 + t;
    srow[i] = s >> 2;
    sgc[i]  = (s & 3) ^ ((srow[i] >> 1) & 3);
  }
  const unsigned lbase = (unsigned)(wv * 1024);  // wave-uniform within i-slab

  auto stage = [&](int p, int k0) {
#pragma unroll
    for (int i = 0; i < 2; ++i) {
      unsigned off = (unsigned)(p * 16384 + i * 4096) + lbase;
      GLOAD_LDS16(A  + (size_t)(m0 + srow[i]) * D_DIM + k0 + sgc[i] * 8, smem + off);
      GLOAD_LDS16(Bm + (size_t)(n0 + srow[i]) * D_DIM + k0 + sgc[i] * 8, smem + 8192 + off);
    }
  };

  stage(0, 0);
  for (int it = 0; it < D_DIM / BK; ++it) {
    __syncthreads();                       // drains tile-it DMA (issued last iter)
    if (it < D_DIM / BK - 1) stage((it + 1) & 1, (it + 1) * BK);
    const char* Ab = smem + (it & 1) * 16384;
    const char* Bb = Ab + 8192;

    bf16x8 af[4], bfr[4];
#pragma unroll
    for (int i = 0; i < 4; ++i) {
      int mrow = wm + i * 16 + lrow;
      int ck   = q ^ ((mrow >> 1) & 3);
      af[i] = *(const bf16x8*)(Ab + (size_t)mrow * (BK * 2) + ck * 16);
      int nrow = wn + i * 16 + lrow;
      int ckb  = q ^ ((nrow >> 1) & 3);
      bfr[i] = *(const bf16x8*)(Bb + (size_t)nrow * (BK * 2) + ckb * 16);
    }
#pragma unroll
    for (int i = 0; i < 4; ++i)
#pragma unroll
      for (int j = 0; j < 4; ++j)
        acc[i][j] = __builtin_amdgcn_mfma_f32_16x16x32_bf16(af[i], bfr[j], acc[i][j], 0, 0, 0);
  }

  // --- epilogue: per-wave LDS transpose, then coalesced float4 stores ---
  __syncthreads();   // all waves done reading buffers
  float* ep = (float*)smem + (size_t)wv * (16 * EP_ROWP);

  float bvj[4];
#pragma unroll
  for (int j = 0; j < 4; ++j) bvj[j] = bias[n0 + wn + j * 16 + lrow];

#pragma unroll
  for (int i = 0; i < 4; ++i) {
#pragma unroll
    for (int j = 0; j < 4; ++j)
#pragma unroll
      for (int r = 0; r < 4; ++r)
        ep[(q * 4 + r) * EP_ROWP + j * 16 + lrow] = acc[i][j][r] + bvj[j];
#pragma unroll
    for (int it = 0; it < 4; ++it) {
      int flat = it * 64 + lane;
      int row  = flat >> 4;
      int c4   = flat & 15;
      float4 v = *(const float4*)(ep + row * EP_ROWP + c4 * 4);
      int gm = m0 + wm + i * 16 + row;
      int gn = n0 + wn + c4 * 4;
      *(float4*)(C + (size_t)gm * D_DIM + gn) = v;
    }
    __syncthreads();
  }
}

// ---------------------------------------------------------------------------
// Fallback (only if workspace is too small): correct but slow fp32 path.
// ---------------------------------------------------------------------------
__global__ __launch_bounds__(256) void fallback_kernel(
    const float* __restrict__ x, const float* __restrict__ w_dw,
    const float* __restrict__ b_dw, const float* __restrict__ w_pw,
    const float* __restrict__ b_pw, float* __restrict__ out) {
  __shared__ float ys[D_DIM];
  const int m = blockIdx.x;
  const int l = m & (L_SEQ - 1);
  const int t = threadIdx.x;
  const float* xr = x + (size_t)m * D_DIM;
#pragma unroll
  for (int c = 0; c < 4; ++c) {
    int d = t + c * 256;
    float a = fmaf(xr[d], w_dw[d * 3 + 2], b_dw[d]);
    if (l >= 1) a = fmaf(xr[d - D_DIM], w_dw[d * 3 + 1], a);
    if (l >= 2) a = fmaf(xr[d - 2 * D_DIM], w_dw[d * 3 + 0], a);
    ys[d] = a;
  }
  __syncthreads();
#pragma unroll
  for (int c = 0; c < 4; ++c) {
    int e = t + c * 256;
    const float* wr = w_pw + (size_t)e * D_DIM;
    float a = b_pw[e];
    for (int d = 0; d < D_DIM; ++d) a = fmaf(ys[d], wr[d], a);
    out[(size_t)m * D_DIM + e] = a;
  }
}

extern "C" void kernel_launch(void* const* d_in, const int* in_sizes, int n_in,
                              void* d_out, int out_size, void* d_ws, size_t ws_size,
                              hipStream_t stream) {
  (void)in_sizes; (void)n_in; (void)out_size;
  const float* x    = (const float*)d_in[0];
  const float* w_dw = (const float*)d_in[1];
  const float* b_dw = (const float*)d_in[2];
  const float* w_pw = (const float*)d_in[3];
  const float* b_pw = (const float*)d_in[4];
  float* out = (float*)d_out;

  const size_t y_elems = (size_t)M_TOT * D_DIM;          // 16M bf16 = 32 MB
  const size_t w_elems = (size_t)D_DIM * D_DIM;          // 1M bf16  =  2 MB
  const size_t need = (y_elems + w_elems) * sizeof(bf16);

  if (ws_size >= need) {
    bf16* y    = (bf16*)d_ws;
    bf16* wpwb = (bf16*)d_ws + y_elems;
    const int cvt_blocks = (D_DIM * D_DIM / 8) / 256;    // 512
    dw_bf16_kernel<<<M_TOT + cvt_blocks, 256, 0, stream>>>(x, w_dw, b_dw, y, w_pw, wpwb);
    dim3 grid(D_DIM / BN, M_TOT / BM);                   // (8, 128)
    gemm_bt_kernel<<<grid, 256, 0, stream>>>(y, wpwb, b_pw, out);
  } else {
    fallback_kernel<<<M_TOT, 256, 0, stream>>>(x, w_dw, b_dw, w_pw, b_pw, out);
  }
}

// Round 4
// 168.200 us; speedup vs baseline: 1.2162x; 1.2162x over previous
//
#include <hip/hip_runtime.h>
#include <hip/hip_bf16.h>
#include <stdint.h>

// Problem constants (B=4, L=4096, D=1024, K=3)
#define B_SZ   4
#define L_SEQ  4096
#define D_DIM  1024
#define M_TOT  (B_SZ * L_SEQ)   // 16384

typedef __bf16 bf16;
typedef __attribute__((ext_vector_type(8))) __bf16 bf16x8;
typedef __attribute__((ext_vector_type(4))) float   f32x4;

#define GLOAD_LDS16(g, l)                                                     \
  __builtin_amdgcn_global_load_lds(                                           \
      (const __attribute__((address_space(1))) void*)(g),                     \
      (__attribute__((address_space(3))) void*)(l), 16, 0, 0)

// ---------------------------------------------------------------------------
// Kernel 1: causal depthwise conv (K=3) + bf16 cast. Max-ILP halo form:
// block = (batch, 16-row l-chunk), thread = 4 channels. 18 INDEPENDENT
// float4 loads (16 rows + 2 halo; x read 1.125x), then 16 fused conv+cast
// stores. 1024 blocks (4/CU). Blocks >= M_TOT/16 do w_pw fp32->bf16 instead.
// ---------------------------------------------------------------------------
__global__ __launch_bounds__(256) void dw_bf16_kernel(
    const float* __restrict__ x, const float* __restrict__ w_dw,
    const float* __restrict__ b_dw, bf16* __restrict__ y,
    const float* __restrict__ w_pw, bf16* __restrict__ wpwb) {
  const int t = threadIdx.x;
  if (blockIdx.x >= B_SZ * (L_SEQ / 16)) {
    // --- w_pw fp32 -> bf16 (512 blocks x 256 thr x 8 elems = 1M) ---
    int i = ((blockIdx.x - B_SZ * (L_SEQ / 16)) * 256 + t) * 8;
    float4 a = *(const float4*)(w_pw + i);
    float4 b = *(const float4*)(w_pw + i + 4);
    union { bf16 h[8]; int4 v; } r;
    r.h[0] = (bf16)a.x; r.h[1] = (bf16)a.y; r.h[2] = (bf16)a.z; r.h[3] = (bf16)a.w;
    r.h[4] = (bf16)b.x; r.h[5] = (bf16)b.y; r.h[6] = (bf16)b.z; r.h[7] = (bf16)b.w;
    *(int4*)(wpwb + i) = r.v;
    return;
  }
  const int b  = blockIdx.x >> 8;     // / (L_SEQ/16 = 256)
  const int l0 = (blockIdx.x & 255) * 16;
  const int d0 = t * 4;
  const float* xb = x + (size_t)b * L_SEQ * D_DIM + d0;
  bf16*        yb = y + (size_t)b * L_SEQ * D_DIM + d0;

  // 18 independent row loads (rows l0-2 .. l0+15)
  float4 xr[18];
  const float4 zero = make_float4(0.f, 0.f, 0.f, 0.f);
  xr[0] = (l0 >= 2) ? *(const float4*)(xb + (size_t)(l0 - 2) * D_DIM) : zero;
  xr[1] = (l0 >= 1) ? *(const float4*)(xb + (size_t)(l0 - 1) * D_DIM) : zero;
#pragma unroll
  for (int j = 0; j < 16; ++j)
    xr[j + 2] = *(const float4*)(xb + (size_t)(l0 + j) * D_DIM);

  // weights: rows d0..d0+3 = 12 contiguous floats at w_dw + d0*3
  const float* wp = w_dw + d0 * 3;
  float4 wa = *(const float4*)(wp);      // d0:k0,k1,k2  d1:k0
  float4 wb = *(const float4*)(wp + 4);  // d1:k1,k2     d2:k0,k1
  float4 wc = *(const float4*)(wp + 8);  // d2:k2        d3:k0,k1,k2
  float4 bv = *(const float4*)(b_dw + d0);

#pragma unroll
  for (int j = 0; j < 16; ++j) {
    float4 x2 = xr[j], x1 = xr[j + 1], x0 = xr[j + 2];
    float a0 = fmaf(x2.x, wa.x, fmaf(x1.x, wa.y, fmaf(x0.x, wa.z, bv.x)));
    float a1 = fmaf(x2.y, wa.w, fmaf(x1.y, wb.x, fmaf(x0.y, wb.y, bv.y)));
    float a2 = fmaf(x2.z, wb.z, fmaf(x1.z, wb.w, fmaf(x0.z, wc.x, bv.z)));
    float a3 = fmaf(x2.w, wc.y, fmaf(x1.w, wc.z, fmaf(x0.w, wc.w, bv.w)));
    union { bf16 h[4]; int2 v; } o;
    o.h[0] = (bf16)a0; o.h[1] = (bf16)a1; o.h[2] = (bf16)a2; o.h[3] = (bf16)a3;
    *(int2*)(yb + (size_t)(l0 + j) * D_DIM) = o.v;
  }
}

// ---------------------------------------------------------------------------
// Kernel 2: GEMM  out[m][n] = sum_k y[m][k] * w_pw[n][k] + b_pw[n]
// M=16384, N=1024, K=1024. BM=BN=128, BK=32, single-barrier double-buffer:
//   stage(0); for it: { barrier; stage(it+1 -> other buf); compute(it); }
// vmcnt drain at the barrier covers DMAs issued a full compute phase earlier.
// GRID (m=x fastest, n=y): linear id = mb + nb*128 -> XCD = mb%8, so all 8
// n-blocks of an m-block share an XCD => A staged ~once from HBM (round-2's
// measured 41MB FETCH; round-3's transpose exploded it to 133MB — reverted).
// LDS: 2 x (A 8KB + B 8KB) = 32KB. Swizzle: slot s -> row=s>>2,
// gc=(s&3)^((row>>1)&3); frag read ck = q ^ ((row>>1)&3).
// Epilogue: per-wave LDS transpose -> float4 stores (exact 64MB writes).
// ---------------------------------------------------------------------------
#define BM 128
#define BN 128
#define BK 32
#define EP_ROWP 68   // fp32 per padded epilogue row

__global__ __launch_bounds__(256) void gemm_bt_kernel(
    const bf16* __restrict__ A,   // M x K row-major (y, bf16)
    const bf16* __restrict__ Bm,  // N x K row-major (w_pw, bf16)
    const float* __restrict__ bias, float* __restrict__ C) {
  __shared__ __align__(16) char smem[32768];
  // buf p: A at p*16384, B at p*16384 + 8192

  const int t    = threadIdx.x;
  const int m0   = blockIdx.x * BM;   // grid.x = 128 (m) — fastest
  const int n0   = blockIdx.y * BN;   // grid.y = 8   (n)
  const int lane = t & 63;
  const int wv   = t >> 6;
  const int wm   = (wv >> 1) * 64;
  const int wn   = (wv & 1) * 64;
  const int lrow = lane & 15;
  const int q    = lane >> 4;

  f32x4 acc[4][4] = {};

  // staging slot geometry: s = i*256 + t, i<2; 512 slots x 16B = 8KB tile
  int srow[2], sgc[2];
#pragma unroll
  for (int i = 0; i < 2; ++i) {
    int s   = i * 256 + t;
    srow[i] = s >> 2;
    sgc[i]  = (s & 3) ^ ((srow[i] >> 1) & 3);
  }
  const unsigned lbase = (unsigned)(wv * 1024);  // wave-uniform within i-slab

  auto stage = [&](int p, int k0) {
#pragma unroll
    for (int i = 0; i < 2; ++i) {
      unsigned off = (unsigned)(p * 16384 + i * 4096) + lbase;
      GLOAD_LDS16(A  + (size_t)(m0 + srow[i]) * D_DIM + k0 + sgc[i] * 8, smem + off);
      GLOAD_LDS16(Bm + (size_t)(n0 + srow[i]) * D_DIM + k0 + sgc[i] * 8, smem + 8192 + off);
    }
  };

  stage(0, 0);
  for (int it = 0; it < D_DIM / BK; ++it) {
    __syncthreads();                       // drains tile-it DMA (issued last iter)
    if (it < D_DIM / BK - 1) stage((it + 1) & 1, (it + 1) * BK);
    const char* Ab = smem + (it & 1) * 16384;
    const char* Bb = Ab + 8192;

    bf16x8 af[4], bfr[4];
#pragma unroll
    for (int i = 0; i < 4; ++i) {
      int mrow = wm + i * 16 + lrow;
      int ck   = q ^ ((mrow >> 1) & 3);
      af[i] = *(const bf16x8*)(Ab + (size_t)mrow * (BK * 2) + ck * 16);
      int nrow = wn + i * 16 + lrow;
      int ckb  = q ^ ((nrow >> 1) & 3);
      bfr[i] = *(const bf16x8*)(Bb + (size_t)nrow * (BK * 2) + ckb * 16);
    }
#pragma unroll
    for (int i = 0; i < 4; ++i)
#pragma unroll
      for (int j = 0; j < 4; ++j)
        acc[i][j] = __builtin_amdgcn_mfma_f32_16x16x32_bf16(af[i], bfr[j], acc[i][j], 0, 0, 0);
  }

  // --- epilogue: per-wave LDS transpose, then coalesced float4 stores ---
  __syncthreads();   // all waves done reading staging buffers
  float* ep = (float*)smem + (size_t)wv * (16 * EP_ROWP);  // wave-private

  float bvj[4];
#pragma unroll
  for (int j = 0; j < 4; ++j) bvj[j] = bias[n0 + wn + j * 16 + lrow];

#pragma unroll
  for (int i = 0; i < 4; ++i) {
#pragma unroll
    for (int j = 0; j < 4; ++j)
#pragma unroll
      for (int r = 0; r < 4; ++r)
        ep[(q * 4 + r) * EP_ROWP + j * 16 + lrow] = acc[i][j][r] + bvj[j];
    // wave-private region: in-wave DS program order suffices, no barrier
#pragma unroll
    for (int it = 0; it < 4; ++it) {
      int flat = it * 64 + lane;
      int row  = flat >> 4;
      int c4   = flat & 15;
      float4 v = *(const float4*)(ep + row * EP_ROWP + c4 * 4);
      int gm = m0 + wm + i * 16 + row;
      int gn = n0 + wn + c4 * 4;
      *(float4*)(C + (size_t)gm * D_DIM + gn) = v;
    }
  }
}

// ---------------------------------------------------------------------------
// Fallback (only if workspace is too small): correct but slow fp32 path.
// ---------------------------------------------------------------------------
__global__ __launch_bounds__(256) void fallback_kernel(
    const float* __restrict__ x, const float* __restrict__ w_dw,
    const float* __restrict__ b_dw, const float* __restrict__ w_pw,
    const float* __restrict__ b_pw, float* __restrict__ out) {
  __shared__ float ys[D_DIM];
  const int m = blockIdx.x;
  const int l = m & (L_SEQ - 1);
  const int t = threadIdx.x;
  const float* xr = x + (size_t)m * D_DIM;
#pragma unroll
  for (int c = 0; c < 4; ++c) {
    int d = t + c * 256;
    float a = fmaf(xr[d], w_dw[d * 3 + 2], b_dw[d]);
    if (l >= 1) a = fmaf(xr[d - D_DIM], w_dw[d * 3 + 1], a);
    if (l >= 2) a = fmaf(xr[d - 2 * D_DIM], w_dw[d * 3 + 0], a);
    ys[d] = a;
  }
  __syncthreads();
#pragma unroll
  for (int c = 0; c < 4; ++c) {
    int e = t + c * 256;
    const float* wr = w_pw + (size_t)e * D_DIM;
    float a = b_pw[e];
    for (int d = 0; d < D_DIM; ++d) a = fmaf(ys[d], wr[d], a);
    out[(size_t)m * D_DIM + e] = a;
  }
}

extern "C" void kernel_launch(void* const* d_in, const int* in_sizes, int n_in,
                              void* d_out, int out_size, void* d_ws, size_t ws_size,
                              hipStream_t stream) {
  (void)in_sizes; (void)n_in; (void)out_size;
  const float* x    = (const float*)d_in[0];
  const float* w_dw = (const float*)d_in[1];
  const float* b_dw = (const float*)d_in[2];
  const float* w_pw = (const float*)d_in[3];
  const float* b_pw = (const float*)d_in[4];
  float* out = (float*)d_out;

  const size_t y_elems = (size_t)M_TOT * D_DIM;          // 16M bf16 = 32 MB
  const size_t w_elems = (size_t)D_DIM * D_DIM;          // 1M bf16  =  2 MB
  const size_t need = (y_elems + w_elems) * sizeof(bf16);

  if (ws_size >= need) {
    bf16* y    = (bf16*)d_ws;
    bf16* wpwb = (bf16*)d_ws + y_elems;
    const int dw_blocks  = B_SZ * (L_SEQ / 16);          // 1024
    const int cvt_blocks = (D_DIM * D_DIM / 8) / 256;    // 512
    dw_bf16_kernel<<<dw_blocks + cvt_blocks, 256, 0, stream>>>(x, w_dw, b_dw, y, w_pw, wpwb);
    dim3 grid(M_TOT / BM, D_DIM / BN);                   // (128, 8): m fastest
    gemm_bt_kernel<<<grid, 256, 0, stream>>>(y, wpwb, b_pw, out);
  } else {
    fallback_kernel<<<M_TOT, 256, 0, stream>>>(x, w_dw, b_dw, w_pw, b_pw, out);
  }
}